// Round 10
// baseline (383.664 us; speedup 1.0000x reference)
//
#include <hip/hip_runtime.h>
#include <hip/hip_bf16.h>
#include <cmath>

#define D_MODEL 1024
#define NHEADS 16
#define HDIM 64
#define BATCH 2
#define SEQ 2048
#define MROWS (BATCH*SEQ)   // 4096
#define KDIM 1024

// ---- DIAGNOSTIC ROUND (R10): idempotent repeats surface all 4 kernels above ----
// ---- the 43us fill threshold with fresh counters. Revert to 1 next round.  ----
#define REP_CVT  6
#define REP_QKV  3
#define REP_ATTN 3
#define REP_O    6

typedef unsigned short ushort_t;
typedef unsigned int uint32;
typedef __attribute__((ext_vector_type(8))) short short8;
typedef __attribute__((ext_vector_type(4))) short short4b;
typedef __attribute__((ext_vector_type(4))) float floatx4;

#define QSCALE 0.1803368801111204f   /* 0.125 * log2(e): scores land in exp2 domain */
#define EXP2F(x) __builtin_amdgcn_exp2f(x)

__device__ __forceinline__ ushort_t f2bf(float x) {
    union { float f; uint32 u; } v; v.f = x;
    uint32 r = v.u + 0x7FFFu + ((v.u >> 16) & 1u);
    return (ushort_t)(r >> 16);
}

__device__ __forceinline__ uint32 pkbf(float a, float b) {
    union { __hip_bfloat162 h2; uint32 u; } v;
    v.h2 = __float22bfloat162_rn(make_float2(a, b));
    return v.u;
}

__device__ __forceinline__ void glds16(const void* g, void* l) {
    __builtin_amdgcn_global_load_lds(
        (const __attribute__((address_space(1))) void*)g,
        (__attribute__((address_space(3))) void*)l, 16, 0, 0);
}

// ---------------- fused conversions: z<4 -> W transpose, z==4 -> x cvt ----------------
__global__ __launch_bounds__(256)
void cvt_all(const float* __restrict__ x, const float* __restrict__ W0,
             const float* __restrict__ W1, const float* __restrict__ W2,
             const float* __restrict__ W3, ushort_t* __restrict__ xb,
             ushort_t* __restrict__ WtQKV, ushort_t* __restrict__ WtO)
{
    const int z = blockIdx.z;
    __shared__ float tl[32][33];
    #pragma unroll 1
    for (int rep = 0; rep < REP_CVT; ++rep) {
        if (z == 4) {
            size_t idx = ((size_t)blockIdx.y * 32 + blockIdx.x) * 256 + threadIdx.x;
            #pragma unroll
            for (int l = 0; l < 4; ++l) {
                size_t i = ((size_t)l * 262144 + idx) * 4;
                float4 v = *(const float4*)(x + i);
                uint2 o;
                o.x = pkbf(v.x, v.y);
                o.y = pkbf(v.z, v.w);
                *(uint2*)(xb + i) = o;
            }
        } else {
            const float* W = (z == 0) ? W0 : (z == 1) ? W1 : (z == 2) ? W2 : W3;
            ushort_t* out = (z < 3) ? (WtQKV + (size_t)z * D_MODEL * KDIM) : WtO;
            const int k0 = blockIdx.x * 32, n0 = blockIdx.y * 32;
            const int tx = threadIdx.x & 31, ty = threadIdx.x >> 5;
            #pragma unroll
            for (int i = 0; i < 4; ++i)
                tl[ty + i * 8][tx] = W[(size_t)(k0 + ty + i * 8) * D_MODEL + n0 + tx];
            __syncthreads();
            #pragma unroll
            for (int i = 0; i < 4; ++i)
                out[(size_t)(n0 + ty + i * 8) * KDIM + k0 + tx] = f2bf(tl[tx][ty + i * 8]);
        }
        __syncthreads();
    }
}

// ---------------- QKV GEMM (R11 proven) + T1 XCD-chunked block swizzle ----------------
__global__ __launch_bounds__(128, 2)
void gemm_qkv(const ushort_t* __restrict__ A, const ushort_t* __restrict__ Bt,
              const float* __restrict__ b0, const float* __restrict__ b1,
              const float* __restrict__ b2, ushort_t* __restrict__ Qb,
              ushort_t* __restrict__ Kb, ushort_t* __restrict__ Vb)
{
    __shared__ ushort_t As[128 * 64];   // 16 KB
    __shared__ ushort_t Bs[128 * 64];   // 16 KB

    const int tid = threadIdx.x;
    const int w = tid >> 6, lane = tid & 63;
    const int quad = lane >> 4, col = lane & 15;
    const int flat = blockIdx.y * 24 + blockIdx.x;    // dispatch order (x-fastest)
    const int xcd = flat & 7, ii = flat >> 3;         // ii in [0,96)
    const int nf = xcd * 96 + ii;                     // contiguous chunk per XCD
    const int m0 = (nf / 24) * 128, n0 = (nf % 24) * 128;

    #pragma unroll 1
    for (int rep = 0; rep < REP_QKV; ++rep) {
        floatx4 zero = {0.f, 0.f, 0.f, 0.f};
        floatx4 acc[4][8];
        #pragma unroll
        for (int i = 0; i < 4; ++i)
            #pragma unroll
            for (int j = 0; j < 8; ++j) acc[i][j] = zero;

        #pragma unroll 1
        for (int k0 = 0; k0 < KDIM; k0 += 64) {
            #pragma unroll
            for (int i = 0; i < 8; ++i) {
                int c = i * 128 + tid;
                int row = c >> 3;
                int kc = (c & 7) ^ (row & 7);
                glds16(A  + (size_t)(m0 + row) * KDIM + k0 + kc * 8, As + (i * 128 + w * 64) * 8);
                glds16(Bt + (size_t)(n0 + row) * KDIM + k0 + kc * 8, Bs + (i * 128 + w * 64) * 8);
            }
            __syncthreads();
            #pragma unroll
            for (int ks = 0; ks < 2; ++ks) {
                short8 af[4], bfr[8];
                const int kc = ks * 4 + quad;
                #pragma unroll
                for (int mt = 0; mt < 4; ++mt) {
                    int r = w * 64 + mt * 16 + col;
                    af[mt] = *(const short8*)(As + ((size_t)r * 8 + (kc ^ (r & 7))) * 8);
                }
                #pragma unroll
                for (int nt = 0; nt < 8; ++nt) {
                    int r = nt * 16 + col;
                    bfr[nt] = *(const short8*)(Bs + ((size_t)r * 8 + (kc ^ (r & 7))) * 8);
                }
                #pragma unroll
                for (int mt = 0; mt < 4; ++mt)
                    #pragma unroll
                    for (int nt = 0; nt < 8; ++nt)
                        acc[mt][nt] = __builtin_amdgcn_mfma_f32_16x16x32_bf16(
                            af[mt], bfr[nt], acc[mt][nt], 0, 0, 0);
            }
            __syncthreads();
        }

        const int which = n0 >> 10;
        const float* bp = (which == 0) ? b0 : (which == 1) ? b1 : b2;
        if (which < 2) {
            ushort_t* outp = (which == 0) ? Qb : Kb;
            const float scl = (which == 0) ? QSCALE : 1.0f;
            #pragma unroll
            for (int mt = 0; mt < 4; ++mt)
                #pragma unroll
                for (int nt = 0; nt < 8; ++nt) {
                    int nn = (n0 + nt * 16 + col) & 1023;
                    float bb = bp[nn];
                    int h = nn >> 6, d = nn & 63;
                    #pragma unroll
                    for (int r = 0; r < 4; ++r) {
                        int m = m0 + w * 64 + mt * 16 + quad * 4 + r;
                        int b = m >> 11, s = m & 2047;
                        outp[((size_t)(b * NHEADS + h) * SEQ + s) * HDIM + d] =
                            f2bf((acc[mt][nt][r] + bb) * scl);
                    }
                }
        } else {
            // V -> [b,h,d,s] transposed, packed 8B stores
            #pragma unroll
            for (int mt = 0; mt < 4; ++mt)
                #pragma unroll
                for (int nt = 0; nt < 8; ++nt) {
                    int nn = (n0 + nt * 16 + col) & 1023;
                    float bb = bp[nn];
                    int h = nn >> 6, d = nn & 63;
                    int mb = m0 + w * 64 + mt * 16 + quad * 4;
                    int b = mb >> 11, s = mb & 2047;
                    uint2 pw;
                    pw.x = pkbf(acc[mt][nt][0] + bb, acc[mt][nt][1] + bb);
                    pw.y = pkbf(acc[mt][nt][2] + bb, acc[mt][nt][3] + bb);
                    *(uint2*)(Vb + ((size_t)(b * NHEADS + h) * HDIM + d) * SEQ + s) = pw;
                }
        }
        __syncthreads();
    }
}

// ---------------- out-projection GEMM v2 + T1 XCD-chunked block swizzle --------------
__global__ __launch_bounds__(128, 2)
void gemm_o(const ushort_t* __restrict__ A, const ushort_t* __restrict__ Bt,
            const float* __restrict__ b0, float* __restrict__ Cf)
{
    __shared__ ushort_t As[128 * 64];   // 16 KB
    __shared__ ushort_t Bs[64 * 64];    //  8 KB

    const int tid = threadIdx.x;
    const int w = tid >> 6, lane = tid & 63;
    const int quad = lane >> 4, col = lane & 15;
    const int flat = blockIdx.y * 16 + blockIdx.x;    // dispatch order (x-fastest)
    const int xcd = flat & 7, ii = flat >> 3;         // ii in [0,64)
    const int nf = xcd * 64 + ii;                     // contiguous chunk per XCD
    const int m0 = (nf / 16) * 128, n0 = (nf % 16) * 64;

    #pragma unroll 1
    for (int rep = 0; rep < REP_O; ++rep) {
        floatx4 zero = {0.f, 0.f, 0.f, 0.f};
        floatx4 acc[4][4];
        #pragma unroll
        for (int i = 0; i < 4; ++i)
            #pragma unroll
            for (int j = 0; j < 4; ++j) acc[i][j] = zero;

        #pragma unroll 1
        for (int k0 = 0; k0 < KDIM; k0 += 64) {
            #pragma unroll
            for (int i = 0; i < 8; ++i) {
                int c = i * 128 + tid;
                int row = c >> 3;
                int kc = (c & 7) ^ (row & 7);
                glds16(A + (size_t)(m0 + row) * KDIM + k0 + kc * 8, As + (i * 128 + w * 64) * 8);
            }
            #pragma unroll
            for (int i = 0; i < 4; ++i) {
                int c = i * 128 + tid;
                int row = c >> 3;
                int kc = (c & 7) ^ (row & 7);
                glds16(Bt + (size_t)(n0 + row) * KDIM + k0 + kc * 8, Bs + (i * 128 + w * 64) * 8);
            }
            __syncthreads();
            #pragma unroll
            for (int ks = 0; ks < 2; ++ks) {
                short8 af[4], bfr[4];
                const int kc = ks * 4 + quad;
                #pragma unroll
                for (int mt = 0; mt < 4; ++mt) {
                    int r = w * 64 + mt * 16 + col;
                    af[mt] = *(const short8*)(As + ((size_t)r * 8 + (kc ^ (r & 7))) * 8);
                }
                #pragma unroll
                for (int nt = 0; nt < 4; ++nt) {
                    int r = nt * 16 + col;
                    bfr[nt] = *(const short8*)(Bs + ((size_t)r * 8 + (kc ^ (r & 7))) * 8);
                }
                #pragma unroll
                for (int mt = 0; mt < 4; ++mt)
                    #pragma unroll
                    for (int nt = 0; nt < 4; ++nt)
                        acc[mt][nt] = __builtin_amdgcn_mfma_f32_16x16x32_bf16(
                            af[mt], bfr[nt], acc[mt][nt], 0, 0, 0);
            }
            __syncthreads();
        }

        #pragma unroll
        for (int mt = 0; mt < 4; ++mt)
            #pragma unroll
            for (int nt = 0; nt < 4; ++nt) {
                int n = n0 + nt * 16 + col;
                float bb = b0[n];
                #pragma unroll
                for (int r = 0; r < 4; ++r) {
                    int m = m0 + w * 64 + mt * 16 + quad * 4 + r;
                    Cf[(size_t)m * D_MODEL + n] = acc[mt][nt][r] + bb;
                }
            }
        __syncthreads();
    }
}

// ---------------- flash causal attention v14: pipelined QK^T, 3-buffer LDS ----------
__global__ __launch_bounds__(256)
void attn_mfma(const ushort_t* __restrict__ Q, const ushort_t* __restrict__ K,
               const ushort_t* __restrict__ Vt, ushort_t* __restrict__ H)
{
    __shared__ __align__(16) float smemf[16640];           // 65 KB
    ushort_t* Qs  = (ushort_t*)smemf;                      // [64][64]
    ushort_t* Ksb = (ushort_t*)(smemf + 2048);             // 3 x [64*64]
    ushort_t* Vsb = (ushort_t*)(smemf + 8192);             // 3 x [64*64]
    float* Ored = smemf;                                   // [4][64q][64d] swizzled
    float* Lred = smemf + 16384;                           // [4][64]

    const int tid = threadIdx.x;
    const int w = tid >> 6, lane = tid & 63;
    const int quad = lane >> 4, col = lane & 15;
    const int blk = blockIdx.x;                       // 0..511
    const int bh = (blk & 7) * 4 + ((blk >> 3) & 3);  // XCD-grouped
    const int pair = blk >> 5;                        // 0..15
    const size_t base = (size_t)bh * SEQ * HDIM;
    const ushort_t* Kb = K + base;
    const ushort_t* Vb = Vt + base;
    const int b = bh >> 4, h = bh & 15;

    const int c0 = (w * 2 + 0) * 64 + lane;
    const int c1 = (w * 2 + 1) * 64 + lane;
    const int r0 = c0 >> 3, o0 = ((c0 & 7) ^ (r0 & 7)) * 8;
    const int r1 = c1 >> 3, o1 = ((c1 & 7) ^ (r1 & 7)) * 8;

    const int rk = w * 16 + col;          // wave's K row (kpos slice base + col)
    const floatx4 zero = {0.f, 0.f, 0.f, 0.f};

    #pragma unroll 1
    for (int rep = 0; rep < REP_ATTN; ++rep) {
    #pragma unroll 1
    for (int pi = 0; pi < 2; ++pi) {
        const int qt = pi ? pair : 31 - pair;
        const int q0 = qt * 64;
        const int nt = qt + 1;

        __syncthreads();     // previous q-tile's epilogue readers of Ored done
        #pragma unroll
        for (int i = 0; i < 2; ++i) {
            int c = (w * 2 + i) * 64 + lane;
            int row = c >> 3, kc = (c & 7) ^ (row & 7);
            glds16(Q + base + (size_t)(q0 + row) * HDIM + kc * 8, Qs + (w * 2 + i) * 512);
        }
        glds16(Kb + (size_t)r0 * HDIM + o0, Ksb + (w * 2 + 0) * 512);
        glds16(Kb + (size_t)r1 * HDIM + o1, Ksb + (w * 2 + 1) * 512);
        glds16(Vb + (size_t)r0 * SEQ + o0,  Vsb + (w * 2 + 0) * 512);
        glds16(Vb + (size_t)r1 * SEQ + o1,  Vsb + (w * 2 + 1) * 512);
        if (nt > 1) {
            glds16(Kb + (size_t)(64 + r0) * HDIM + o0, Ksb + 4096 + (w * 2 + 0) * 512);
            glds16(Kb + (size_t)(64 + r1) * HDIM + o1, Ksb + 4096 + (w * 2 + 1) * 512);
            glds16(Vb + (size_t)r0 * SEQ + 64 + o0,    Vsb + 4096 + (w * 2 + 0) * 512);
            glds16(Vb + (size_t)r1 * SEQ + 64 + o1,    Vsb + 4096 + (w * 2 + 1) * 512);
        }
        __syncthreads();     // Qs + buf0 + buf1 ready

        short8 bq[4][2];
        #pragma unroll
        for (int qb = 0; qb < 4; ++qb)
            #pragma unroll
            for (int ks = 0; ks < 2; ++ks) {
                int rq = qb * 16 + col;
                int kc = ks * 4 + quad;
                bq[qb][ks] = *(const short8*)(Qs + ((size_t)rq * 8 + (kc ^ (rq & 7))) * 8);
            }

        floatx4 o_[4][4];
        #pragma unroll
        for (int i = 0; i < 4; ++i)
            #pragma unroll
            for (int j = 0; j < 4; ++j) o_[i][j] = zero;
        float lq[4] = {0.f, 0.f, 0.f, 0.f};

        ushort_t* Kcur = Ksb;            ushort_t* Vcur = Vsb;
        ushort_t* Knxt = Ksb + 4096;     ushort_t* Vnxt = Vsb + 4096;
        ushort_t* Kstg = Ksb + 8192;     ushort_t* Vstg = Vsb + 8192;

        floatx4 scA[4];
        #pragma unroll
        for (int qb = 0; qb < 4; ++qb) scA[qb] = zero;
        __builtin_amdgcn_s_setprio(1);
        #pragma unroll
        for (int ks = 0; ks < 2; ++ks) {
            const int kc = ks * 4 + quad;
            short8 ak = *(const short8*)(Kcur + ((size_t)rk * 8 + (kc ^ (rk & 7))) * 8);
            #pragma unroll
            for (int qb = 0; qb < 4; ++qb)
                scA[qb] = __builtin_amdgcn_mfma_f32_16x16x32_bf16(
                    ak, bq[qb][ks], scA[qb], 0, 0, 0);
        }
        __builtin_amdgcn_s_setprio(0);

        #pragma unroll 1
        for (int t = 0; t < nt; ++t) {
            if (t + 2 < nt) {            // async stage t+2 into stg buffer
                const int k0n = (t + 2) * 64;
                glds16(Kb + (size_t)(k0n + r0) * HDIM + o0, Kstg + (w * 2 + 0) * 512);
                glds16(Kb + (size_t)(k0n + r1) * HDIM + o1, Kstg + (w * 2 + 1) * 512);
                glds16(Vb + (size_t)r0 * SEQ + k0n + o0,    Vstg + (w * 2 + 0) * 512);
                glds16(Vb + (size_t)r1 * SEQ + k0n + o1,    Vstg + (w * 2 + 1) * 512);
            }

            if (t == nt - 1) {
                #pragma unroll
                for (int qb = 0; qb < 4; ++qb)
                    #pragma unroll
                    for (int r = 0; r < 4; ++r)
                        if (w * 16 + quad * 4 + r > qb * 16 + col) scA[qb][r] = -INFINITY;
            }

            short4b bp[4];
            #pragma unroll
            for (int qb = 0; qb < 4; ++qb) {
                float p0 = EXP2F(scA[qb][0]);
                float p1 = EXP2F(scA[qb][1]);
                float p2 = EXP2F(scA[qb][2]);
                float p3 = EXP2F(scA[qb][3]);
                lq[qb] += (p0 + p1) + (p2 + p3);
                union { uint2 u; short4b s; } pv;
                pv.u.x = pkbf(p0, p1);
                pv.u.y = pkbf(p2, p3);
                bp[qb] = pv.s;
            }

            floatx4 scB[4];
            if (t + 1 < nt) {
                #pragma unroll
                for (int qb = 0; qb < 4; ++qb) scB[qb] = zero;
                __builtin_amdgcn_s_setprio(1);
                #pragma unroll
                for (int ks = 0; ks < 2; ++ks) {
                    const int kc = ks * 4 + quad;
                    short8 ak = *(const short8*)(Knxt + ((size_t)rk * 8 + (kc ^ (rk & 7))) * 8);
                    #pragma unroll
                    for (int qb = 0; qb < 4; ++qb)
                        scB[qb] = __builtin_amdgcn_mfma_f32_16x16x32_bf16(
                            ak, bq[qb][ks], scB[qb], 0, 0, 0);
                }
                __builtin_amdgcn_s_setprio(0);
            }

            const int cc = 2 * w + (quad >> 1);    // 8-elem chunk of elems w*16+quad*4
            const int sub = (quad & 1) * 4;
            __builtin_amdgcn_s_setprio(1);
            #pragma unroll
            for (int db = 0; db < 4; ++db) {
                int rv = db * 16 + col;
                short4b av = *(const short4b*)(Vcur + ((size_t)rv * 8 + (cc ^ (rv & 7))) * 8 + sub);
                #pragma unroll
                for (int qb = 0; qb < 4; ++qb)
                    o_[db][qb] = __builtin_amdgcn_mfma_f32_16x16x16bf16_1k(
                        av, bp[qb], o_[db][qb], 0, 0, 0);
            }
            __builtin_amdgcn_s_setprio(0);

            __syncthreads();   // publish stg buffer + fence buffer rotation

            ushort_t* tk = Kcur; Kcur = Knxt; Knxt = Kstg; Kstg = tk;
            ushort_t* tv = Vcur; Vcur = Vnxt; Vnxt = Vstg; Vstg = tv;
            if (t + 1 < nt) {
                #pragma unroll
                for (int qb = 0; qb < 4; ++qb) scA[qb] = scB[qb];
            }
        }

        #pragma unroll
        for (int qb = 0; qb < 4; ++qb) {
            lq[qb] += __shfl_xor(lq[qb], 16);
            lq[qb] += __shfl_xor(lq[qb], 32);
        }
        if (quad == 0) {
            #pragma unroll
            for (int qb = 0; qb < 4; ++qb) Lred[w * 64 + qb * 16 + col] = lq[qb];
        }
        {
            float* myreg = Ored + w * 4096;
            #pragma unroll
            for (int db = 0; db < 4; ++db)
                #pragma unroll
                for (int qb = 0; qb < 4; ++qb) {
                    int q = qb * 16 + col;
                    int swch = (db * 4 + quad) ^ col;
                    *(floatx4*)(myreg + q * 64 + swch * 4) = o_[db][qb];
                }
        }
        __syncthreads();

        {
            const int qloc = w * 16 + (lane >> 2);
            float lsum = Lred[qloc] + Lred[64 + qloc] + Lred[128 + qloc] + Lred[192 + qloc];
            float linv = 1.f / lsum;
            const int dc0 = (lane & 3) * 4;        // 4 d-chunks of 4 floats
            floatx4 acc[4];
            #pragma unroll
            for (int j = 0; j < 4; ++j) {
                int swch = (dc0 + j) ^ (qloc & 15);
                const float* p = Ored + (size_t)qloc * 64 + swch * 4;
                floatx4 a = *(const floatx4*)p;
                a += *(const floatx4*)(p + 4096);
                a += *(const floatx4*)(p + 8192);
                a += *(const floatx4*)(p + 12288);
                acc[j] = a;
            }
            const size_t rowb = ((size_t)(b * SEQ + q0 + qloc)) * D_MODEL + h * HDIM + dc0 * 4;
            uint4 u0, u1;
            u0.x = pkbf(acc[0][0] * linv, acc[0][1] * linv);
            u0.y = pkbf(acc[0][2] * linv, acc[0][3] * linv);
            u0.z = pkbf(acc[1][0] * linv, acc[1][1] * linv);
            u0.w = pkbf(acc[1][2] * linv, acc[1][3] * linv);
            u1.x = pkbf(acc[2][0] * linv, acc[2][1] * linv);
            u1.y = pkbf(acc[2][2] * linv, acc[2][3] * linv);
            u1.z = pkbf(acc[3][0] * linv, acc[3][1] * linv);
            u1.w = pkbf(acc[3][2] * linv, acc[3][3] * linv);
            *(uint4*)(H + rowb) = u0;
            *(uint4*)(H + rowb + 8) = u1;
        }
    }
    }
}

extern "C" void kernel_launch(void* const* d_in, const int* in_sizes, int n_in,
                              void* d_out, int out_size, void* d_ws, size_t ws_size,
                              hipStream_t stream)
{
    (void)in_sizes; (void)n_in; (void)out_size; (void)ws_size;
    const float* x  = (const float*)d_in[0];
    const float* Wq = (const float*)d_in[1];
    const float* bq = (const float*)d_in[2];
    const float* Wk = (const float*)d_in[3];
    const float* bk = (const float*)d_in[4];
    const float* Wv = (const float*)d_in[5];
    const float* bv = (const float*)d_in[6];
    const float* Wo = (const float*)d_in[7];
    const float* bo = (const float*)d_in[8];

    const size_t E = (size_t)MROWS * D_MODEL;
    ushort_t* xb    = (ushort_t*)d_ws;               // [4096][1024] bf16
    ushort_t* WtQKV = xb + E;                        // [3072][1024] bf16
    ushort_t* WtO   = WtQKV + 3 * (size_t)D_MODEL * KDIM;
    ushort_t* Qb    = WtO + (size_t)D_MODEL * KDIM;  // [b,h,s,d] bf16 (pre-scaled)
    ushort_t* Kb    = Qb + E;                        // [b,h,s,d] bf16
    ushort_t* Vb    = Kb + E;                        // [b,h,d,s] bf16 (transposed)
    ushort_t* Hb    = Vb + E;                        // [4096][1024] bf16

    cvt_all<<<dim3(32, 32, 5), 256, 0, stream>>>(x, Wq, Wk, Wv, Wo, xb, WtQKV, WtO);
    gemm_qkv<<<dim3(24, 32), 128, 0, stream>>>(xb, WtQKV, bq, bk, bv, Qb, Kb, Vb);
    attn_mfma<<<dim3(512), 256, 0, stream>>>(Qb, Kb, Vb, Hb);
    gemm_o<<<dim3(16, 32), 128, 0, stream>>>(Hb, WtO, bo, (float*)d_out);
}

// Round 11
// 189.239 us; speedup vs baseline: 2.0274x; 2.0274x over previous
//
#include <hip/hip_runtime.h>
#include <hip/hip_bf16.h>
#include <cmath>

#define D_MODEL 1024
#define NHEADS 16
#define HDIM 64
#define BATCH 2
#define SEQ 2048
#define MROWS (BATCH*SEQ)   // 4096
#define KDIM 1024

typedef unsigned short ushort_t;
typedef unsigned int uint32;
typedef __attribute__((ext_vector_type(8))) short short8;
typedef __attribute__((ext_vector_type(4))) short short4b;
typedef __attribute__((ext_vector_type(4))) float floatx4;

#define QSCALE 0.1803368801111204f   /* 0.125 * log2(e): scores land in exp2 domain */
#define EXP2F(x) __builtin_amdgcn_exp2f(x)

__device__ __forceinline__ ushort_t f2bf(float x) {
    union { float f; uint32 u; } v; v.f = x;
    uint32 r = v.u + 0x7FFFu + ((v.u >> 16) & 1u);
    return (ushort_t)(r >> 16);
}

__device__ __forceinline__ uint32 pkbf(float a, float b) {
    union { __hip_bfloat162 h2; uint32 u; } v;
    v.h2 = __float22bfloat162_rn(make_float2(a, b));
    return v.u;
}

__device__ __forceinline__ void glds16(const void* g, void* l) {
    __builtin_amdgcn_global_load_lds(
        (const __attribute__((address_space(1))) void*)g,
        (__attribute__((address_space(3))) void*)l, 16, 0, 0);
}

// ---------------- fused conversions: z<4 -> W transpose, z==4 -> x cvt ----------------
__global__ __launch_bounds__(256)
void cvt_all(const float* __restrict__ x, const float* __restrict__ W0,
             const float* __restrict__ W1, const float* __restrict__ W2,
             const float* __restrict__ W3, ushort_t* __restrict__ xb,
             ushort_t* __restrict__ WtQKV, ushort_t* __restrict__ WtO)
{
    const int z = blockIdx.z;
    if (z == 4) {
        size_t idx = ((size_t)blockIdx.y * 32 + blockIdx.x) * 256 + threadIdx.x;
        #pragma unroll
        for (int l = 0; l < 4; ++l) {
            size_t i = ((size_t)l * 262144 + idx) * 4;
            float4 v = *(const float4*)(x + i);
            uint2 o;
            o.x = pkbf(v.x, v.y);
            o.y = pkbf(v.z, v.w);
            *(uint2*)(xb + i) = o;
        }
        return;
    }
    __shared__ float tl[32][33];
    const float* W = (z == 0) ? W0 : (z == 1) ? W1 : (z == 2) ? W2 : W3;
    ushort_t* out = (z < 3) ? (WtQKV + (size_t)z * D_MODEL * KDIM) : WtO;
    const int k0 = blockIdx.x * 32, n0 = blockIdx.y * 32;
    const int tx = threadIdx.x & 31, ty = threadIdx.x >> 5;
    #pragma unroll
    for (int i = 0; i < 4; ++i)
        tl[ty + i * 8][tx] = W[(size_t)(k0 + ty + i * 8) * D_MODEL + n0 + tx];
    __syncthreads();
    #pragma unroll
    for (int i = 0; i < 4; ++i)
        out[(size_t)(n0 + ty + i * 8) * KDIM + k0 + tx] = f2bf(tl[tx][ty + i * 8]);
}

// ---------------- QKV GEMM v3: 4 waves (m97 config), 128x128 tile, T1 swizzle --------
// R10 counters (2-wave version): MfmaUtil 27%, VALUBusy 16.5%, Occupancy 14%
// (6 waves/CU) -> latency-bound. v3: 256 threads / 4 waves, each wave owns a
// 64x64 quadrant (acc[4][4], ~half the per-wave VGPR) -> 12 waves/CU. Same tile,
// same glds16 chunk-swizzle staging (4-wave staging validated in R2 phase B),
// same per-fragment MFMA order -> bit-identical output.
__global__ __launch_bounds__(256)
void gemm_qkv(const ushort_t* __restrict__ A, const ushort_t* __restrict__ Bt,
              const float* __restrict__ b0, const float* __restrict__ b1,
              const float* __restrict__ b2, ushort_t* __restrict__ Qb,
              ushort_t* __restrict__ Kb, ushort_t* __restrict__ Vb)
{
    __shared__ ushort_t As[128 * 64];   // 16 KB
    __shared__ ushort_t Bs[128 * 64];   // 16 KB

    const int tid = threadIdx.x;
    const int w = tid >> 6, lane = tid & 63;
    const int quad = lane >> 4, col = lane & 15;
    const int wm = w >> 1, wn = w & 1;                // 2x2 wave grid, 64x64 each
    const int flat = blockIdx.y * 24 + blockIdx.x;    // dispatch order (x-fastest)
    const int xcd = flat & 7, ii = flat >> 3;         // ii in [0,96)
    const int nf = xcd * 96 + ii;                     // contiguous chunk per XCD
    const int m0 = (nf / 24) * 128, n0 = (nf % 24) * 128;

    floatx4 zero = {0.f, 0.f, 0.f, 0.f};
    floatx4 acc[4][4];
    #pragma unroll
    for (int i = 0; i < 4; ++i)
        #pragma unroll
        for (int j = 0; j < 4; ++j) acc[i][j] = zero;

    #pragma unroll 1
    for (int k0 = 0; k0 < KDIM; k0 += 64) {
        #pragma unroll
        for (int i = 0; i < 4; ++i) {
            int c = i * 256 + tid;
            int row = c >> 3;
            int kc = (c & 7) ^ (row & 7);
            glds16(A  + (size_t)(m0 + row) * KDIM + k0 + kc * 8, As + (i * 256 + w * 64) * 8);
            glds16(Bt + (size_t)(n0 + row) * KDIM + k0 + kc * 8, Bs + (i * 256 + w * 64) * 8);
        }
        __syncthreads();
        #pragma unroll
        for (int ks = 0; ks < 2; ++ks) {
            short8 af[4], bfr[4];
            const int kc = ks * 4 + quad;
            #pragma unroll
            for (int mt = 0; mt < 4; ++mt) {
                int r = wm * 64 + mt * 16 + col;
                af[mt] = *(const short8*)(As + ((size_t)r * 8 + (kc ^ (r & 7))) * 8);
            }
            #pragma unroll
            for (int nt = 0; nt < 4; ++nt) {
                int r = wn * 64 + nt * 16 + col;
                bfr[nt] = *(const short8*)(Bs + ((size_t)r * 8 + (kc ^ (r & 7))) * 8);
            }
            #pragma unroll
            for (int mt = 0; mt < 4; ++mt)
                #pragma unroll
                for (int nt = 0; nt < 4; ++nt)
                    acc[mt][nt] = __builtin_amdgcn_mfma_f32_16x16x32_bf16(
                        af[mt], bfr[nt], acc[mt][nt], 0, 0, 0);
        }
        __syncthreads();
    }

    const int which = n0 >> 10;
    const float* bp = (which == 0) ? b0 : (which == 1) ? b1 : b2;
    if (which < 2) {
        ushort_t* outp = (which == 0) ? Qb : Kb;
        const float scl = (which == 0) ? QSCALE : 1.0f;
        #pragma unroll
        for (int mt = 0; mt < 4; ++mt)
            #pragma unroll
            for (int nt = 0; nt < 4; ++nt) {
                int nn = (n0 + wn * 64 + nt * 16 + col) & 1023;
                float bb = bp[nn];
                int h = nn >> 6, d = nn & 63;
                #pragma unroll
                for (int r = 0; r < 4; ++r) {
                    int m = m0 + wm * 64 + mt * 16 + quad * 4 + r;
                    int b = m >> 11, s = m & 2047;
                    outp[((size_t)(b * NHEADS + h) * SEQ + s) * HDIM + d] =
                        f2bf((acc[mt][nt][r] + bb) * scl);
                }
            }
    } else {
        // V -> [b,h,d,s] transposed, packed 8B stores
        #pragma unroll
        for (int mt = 0; mt < 4; ++mt)
            #pragma unroll
            for (int nt = 0; nt < 4; ++nt) {
                int nn = (n0 + wn * 64 + nt * 16 + col) & 1023;
                float bb = bp[nn];
                int h = nn >> 6, d = nn & 63;
                int mb = m0 + wm * 64 + mt * 16 + quad * 4;
                int b = mb >> 11, s = mb & 2047;
                uint2 pw;
                pw.x = pkbf(acc[mt][nt][0] + bb, acc[mt][nt][1] + bb);
                pw.y = pkbf(acc[mt][nt][2] + bb, acc[mt][nt][3] + bb);
                *(uint2*)(Vb + ((size_t)(b * NHEADS + h) * HDIM + d) * SEQ + s) = pw;
            }
    }
}

// ---------------- out-projection GEMM v2 + T1 XCD-chunked block swizzle --------------
__global__ __launch_bounds__(128, 2)
void gemm_o(const ushort_t* __restrict__ A, const ushort_t* __restrict__ Bt,
            const float* __restrict__ b0, float* __restrict__ Cf)
{
    __shared__ ushort_t As[128 * 64];   // 16 KB
    __shared__ ushort_t Bs[64 * 64];    //  8 KB

    const int tid = threadIdx.x;
    const int w = tid >> 6, lane = tid & 63;
    const int quad = lane >> 4, col = lane & 15;
    const int flat = blockIdx.y * 16 + blockIdx.x;    // dispatch order (x-fastest)
    const int xcd = flat & 7, ii = flat >> 3;         // ii in [0,64)
    const int nf = xcd * 64 + ii;                     // contiguous chunk per XCD
    const int m0 = (nf / 16) * 128, n0 = (nf % 16) * 64;

    floatx4 zero = {0.f, 0.f, 0.f, 0.f};
    floatx4 acc[4][4];
    #pragma unroll
    for (int i = 0; i < 4; ++i)
        #pragma unroll
        for (int j = 0; j < 4; ++j) acc[i][j] = zero;

    #pragma unroll 1
    for (int k0 = 0; k0 < KDIM; k0 += 64) {
        #pragma unroll
        for (int i = 0; i < 8; ++i) {
            int c = i * 128 + tid;
            int row = c >> 3;
            int kc = (c & 7) ^ (row & 7);
            glds16(A + (size_t)(m0 + row) * KDIM + k0 + kc * 8, As + (i * 128 + w * 64) * 8);
        }
        #pragma unroll
        for (int i = 0; i < 4; ++i) {
            int c = i * 128 + tid;
            int row = c >> 3;
            int kc = (c & 7) ^ (row & 7);
            glds16(Bt + (size_t)(n0 + row) * KDIM + k0 + kc * 8, Bs + (i * 128 + w * 64) * 8);
        }
        __syncthreads();
        #pragma unroll
        for (int ks = 0; ks < 2; ++ks) {
            short8 af[4], bfr[4];
            const int kc = ks * 4 + quad;
            #pragma unroll
            for (int mt = 0; mt < 4; ++mt) {
                int r = w * 64 + mt * 16 + col;
                af[mt] = *(const short8*)(As + ((size_t)r * 8 + (kc ^ (r & 7))) * 8);
            }
            #pragma unroll
            for (int nt = 0; nt < 4; ++nt) {
                int r = nt * 16 + col;
                bfr[nt] = *(const short8*)(Bs + ((size_t)r * 8 + (kc ^ (r & 7))) * 8);
            }
            #pragma unroll
            for (int mt = 0; mt < 4; ++mt)
                #pragma unroll
                for (int nt = 0; nt < 4; ++nt)
                    acc[mt][nt] = __builtin_amdgcn_mfma_f32_16x16x32_bf16(
                        af[mt], bfr[nt], acc[mt][nt], 0, 0, 0);
        }
        __syncthreads();
    }

    #pragma unroll
    for (int mt = 0; mt < 4; ++mt)
        #pragma unroll
        for (int nt = 0; nt < 4; ++nt) {
            int n = n0 + nt * 16 + col;
            float bb = b0[n];
            #pragma unroll
            for (int r = 0; r < 4; ++r) {
                int m = m0 + w * 64 + mt * 16 + quad * 4 + r;
                Cf[(size_t)m * D_MODEL + n] = acc[mt][nt][r] + bb;
            }
        }
}

// ---------------- flash causal attention v14: pipelined QK^T, 3-buffer LDS ----------
__global__ __launch_bounds__(256)
void attn_mfma(const ushort_t* __restrict__ Q, const ushort_t* __restrict__ K,
               const ushort_t* __restrict__ Vt, ushort_t* __restrict__ H)
{
    __shared__ __align__(16) float smemf[16640];           // 65 KB
    ushort_t* Qs  = (ushort_t*)smemf;                      // [64][64]
    ushort_t* Ksb = (ushort_t*)(smemf + 2048);             // 3 x [64*64]
    ushort_t* Vsb = (ushort_t*)(smemf + 8192);             // 3 x [64*64]
    float* Ored = smemf;                                   // [4][64q][64d] swizzled
    float* Lred = smemf + 16384;                           // [4][64]

    const int tid = threadIdx.x;
    const int w = tid >> 6, lane = tid & 63;
    const int quad = lane >> 4, col = lane & 15;
    const int blk = blockIdx.x;                       // 0..511
    const int bh = (blk & 7) * 4 + ((blk >> 3) & 3);  // XCD-grouped
    const int pair = blk >> 5;                        // 0..15
    const size_t base = (size_t)bh * SEQ * HDIM;
    const ushort_t* Kb = K + base;
    const ushort_t* Vb = Vt + base;
    const int b = bh >> 4, h = bh & 15;

    const int c0 = (w * 2 + 0) * 64 + lane;
    const int c1 = (w * 2 + 1) * 64 + lane;
    const int r0 = c0 >> 3, o0 = ((c0 & 7) ^ (r0 & 7)) * 8;
    const int r1 = c1 >> 3, o1 = ((c1 & 7) ^ (r1 & 7)) * 8;

    const int rk = w * 16 + col;          // wave's K row (kpos slice base + col)
    const floatx4 zero = {0.f, 0.f, 0.f, 0.f};

    #pragma unroll 1
    for (int pi = 0; pi < 2; ++pi) {
        const int qt = pi ? pair : 31 - pair;
        const int q0 = qt * 64;
        const int nt = qt + 1;

        __syncthreads();     // previous q-tile's epilogue readers of Ored done
        #pragma unroll
        for (int i = 0; i < 2; ++i) {
            int c = (w * 2 + i) * 64 + lane;
            int row = c >> 3, kc = (c & 7) ^ (row & 7);
            glds16(Q + base + (size_t)(q0 + row) * HDIM + kc * 8, Qs + (w * 2 + i) * 512);
        }
        glds16(Kb + (size_t)r0 * HDIM + o0, Ksb + (w * 2 + 0) * 512);
        glds16(Kb + (size_t)r1 * HDIM + o1, Ksb + (w * 2 + 1) * 512);
        glds16(Vb + (size_t)r0 * SEQ + o0,  Vsb + (w * 2 + 0) * 512);
        glds16(Vb + (size_t)r1 * SEQ + o1,  Vsb + (w * 2 + 1) * 512);
        if (nt > 1) {
            glds16(Kb + (size_t)(64 + r0) * HDIM + o0, Ksb + 4096 + (w * 2 + 0) * 512);
            glds16(Kb + (size_t)(64 + r1) * HDIM + o1, Ksb + 4096 + (w * 2 + 1) * 512);
            glds16(Vb + (size_t)r0 * SEQ + 64 + o0,    Vsb + 4096 + (w * 2 + 0) * 512);
            glds16(Vb + (size_t)r1 * SEQ + 64 + o1,    Vsb + 4096 + (w * 2 + 1) * 512);
        }
        __syncthreads();     // Qs + buf0 + buf1 ready

        short8 bq[4][2];
        #pragma unroll
        for (int qb = 0; qb < 4; ++qb)
            #pragma unroll
            for (int ks = 0; ks < 2; ++ks) {
                int rq = qb * 16 + col;
                int kc = ks * 4 + quad;
                bq[qb][ks] = *(const short8*)(Qs + ((size_t)rq * 8 + (kc ^ (rq & 7))) * 8);
            }

        floatx4 o_[4][4];
        #pragma unroll
        for (int i = 0; i < 4; ++i)
            #pragma unroll
            for (int j = 0; j < 4; ++j) o_[i][j] = zero;
        float lq[4] = {0.f, 0.f, 0.f, 0.f};

        ushort_t* Kcur = Ksb;            ushort_t* Vcur = Vsb;
        ushort_t* Knxt = Ksb + 4096;     ushort_t* Vnxt = Vsb + 4096;
        ushort_t* Kstg = Ksb + 8192;     ushort_t* Vstg = Vsb + 8192;

        floatx4 scA[4];
        #pragma unroll
        for (int qb = 0; qb < 4; ++qb) scA[qb] = zero;
        __builtin_amdgcn_s_setprio(1);
        #pragma unroll
        for (int ks = 0; ks < 2; ++ks) {
            const int kc = ks * 4 + quad;
            short8 ak = *(const short8*)(Kcur + ((size_t)rk * 8 + (kc ^ (rk & 7))) * 8);
            #pragma unroll
            for (int qb = 0; qb < 4; ++qb)
                scA[qb] = __builtin_amdgcn_mfma_f32_16x16x32_bf16(
                    ak, bq[qb][ks], scA[qb], 0, 0, 0);
        }
        __builtin_amdgcn_s_setprio(0);

        #pragma unroll 1
        for (int t = 0; t < nt; ++t) {
            if (t + 2 < nt) {            // async stage t+2 into stg buffer
                const int k0n = (t + 2) * 64;
                glds16(Kb + (size_t)(k0n + r0) * HDIM + o0, Kstg + (w * 2 + 0) * 512);
                glds16(Kb + (size_t)(k0n + r1) * HDIM + o1, Kstg + (w * 2 + 1) * 512);
                glds16(Vb + (size_t)r0 * SEQ + k0n + o0,    Vstg + (w * 2 + 0) * 512);
                glds16(Vb + (size_t)r1 * SEQ + k0n + o1,    Vstg + (w * 2 + 1) * 512);
            }

            if (t == nt - 1) {
                #pragma unroll
                for (int qb = 0; qb < 4; ++qb)
                    #pragma unroll
                    for (int r = 0; r < 4; ++r)
                        if (w * 16 + quad * 4 + r > qb * 16 + col) scA[qb][r] = -INFINITY;
            }

            short4b bp[4];
            #pragma unroll
            for (int qb = 0; qb < 4; ++qb) {
                float p0 = EXP2F(scA[qb][0]);
                float p1 = EXP2F(scA[qb][1]);
                float p2 = EXP2F(scA[qb][2]);
                float p3 = EXP2F(scA[qb][3]);
                lq[qb] += (p0 + p1) + (p2 + p3);
                union { uint2 u; short4b s; } pv;
                pv.u.x = pkbf(p0, p1);
                pv.u.y = pkbf(p2, p3);
                bp[qb] = pv.s;
            }

            floatx4 scB[4];
            if (t + 1 < nt) {
                #pragma unroll
                for (int qb = 0; qb < 4; ++qb) scB[qb] = zero;
                __builtin_amdgcn_s_setprio(1);
                #pragma unroll
                for (int ks = 0; ks < 2; ++ks) {
                    const int kc = ks * 4 + quad;
                    short8 ak = *(const short8*)(Knxt + ((size_t)rk * 8 + (kc ^ (rk & 7))) * 8);
                    #pragma unroll
                    for (int qb = 0; qb < 4; ++qb)
                        scB[qb] = __builtin_amdgcn_mfma_f32_16x16x32_bf16(
                            ak, bq[qb][ks], scB[qb], 0, 0, 0);
                }
                __builtin_amdgcn_s_setprio(0);
            }

            const int cc = 2 * w + (quad >> 1);    // 8-elem chunk of elems w*16+quad*4
            const int sub = (quad & 1) * 4;
            __builtin_amdgcn_s_setprio(1);
            #pragma unroll
            for (int db = 0; db < 4; ++db) {
                int rv = db * 16 + col;
                short4b av = *(const short4b*)(Vcur + ((size_t)rv * 8 + (cc ^ (rv & 7))) * 8 + sub);
                #pragma unroll
                for (int qb = 0; qb < 4; ++qb)
                    o_[db][qb] = __builtin_amdgcn_mfma_f32_16x16x16bf16_1k(
                        av, bp[qb], o_[db][qb], 0, 0, 0);
            }
            __builtin_amdgcn_s_setprio(0);

            __syncthreads();   // publish stg buffer + fence buffer rotation

            ushort_t* tk = Kcur; Kcur = Knxt; Knxt = Kstg; Kstg = tk;
            ushort_t* tv = Vcur; Vcur = Vnxt; Vnxt = Vstg; Vstg = tv;
            if (t + 1 < nt) {
                #pragma unroll
                for (int qb = 0; qb < 4; ++qb) scA[qb] = scB[qb];
            }
        }

        #pragma unroll
        for (int qb = 0; qb < 4; ++qb) {
            lq[qb] += __shfl_xor(lq[qb], 16);
            lq[qb] += __shfl_xor(lq[qb], 32);
        }
        if (quad == 0) {
            #pragma unroll
            for (int qb = 0; qb < 4; ++qb) Lred[w * 64 + qb * 16 + col] = lq[qb];
        }
        {
            float* myreg = Ored + w * 4096;
            #pragma unroll
            for (int db = 0; db < 4; ++db)
                #pragma unroll
                for (int qb = 0; qb < 4; ++qb) {
                    int q = qb * 16 + col;
                    int swch = (db * 4 + quad) ^ col;
                    *(floatx4*)(myreg + q * 64 + swch * 4) = o_[db][qb];
                }
        }
        __syncthreads();

        {
            const int qloc = w * 16 + (lane >> 2);
            float lsum = Lred[qloc] + Lred[64 + qloc] + Lred[128 + qloc] + Lred[192 + qloc];
            float linv = 1.f / lsum;
            const int dc0 = (lane & 3) * 4;        // 4 d-chunks of 4 floats
            floatx4 acc[4];
            #pragma unroll
            for (int j = 0; j < 4; ++j) {
                int swch = (dc0 + j) ^ (qloc & 15);
                const float* p = Ored + (size_t)qloc * 64 + swch * 4;
                floatx4 a = *(const floatx4*)p;
                a += *(const floatx4*)(p + 4096);
                a += *(const floatx4*)(p + 8192);
                a += *(const floatx4*)(p + 12288);
                acc[j] = a;
            }
            const size_t rowb = ((size_t)(b * SEQ + q0 + qloc)) * D_MODEL + h * HDIM + dc0 * 4;
            uint4 u0, u1;
            u0.x = pkbf(acc[0][0] * linv, acc[0][1] * linv);
            u0.y = pkbf(acc[0][2] * linv, acc[0][3] * linv);
            u0.z = pkbf(acc[1][0] * linv, acc[1][1] * linv);
            u0.w = pkbf(acc[1][2] * linv, acc[1][3] * linv);
            u1.x = pkbf(acc[2][0] * linv, acc[2][1] * linv);
            u1.y = pkbf(acc[2][2] * linv, acc[2][3] * linv);
            u1.z = pkbf(acc[3][0] * linv, acc[3][1] * linv);
            u1.w = pkbf(acc[3][2] * linv, acc[3][3] * linv);
            *(uint4*)(H + rowb) = u0;
            *(uint4*)(H + rowb + 8) = u1;
        }
    }
}

extern "C" void kernel_launch(void* const* d_in, const int* in_sizes, int n_in,
                              void* d_out, int out_size, void* d_ws, size_t ws_size,
                              hipStream_t stream)
{
    (void)in_sizes; (void)n_in; (void)out_size; (void)ws_size;
    const float* x  = (const float*)d_in[0];
    const float* Wq = (const float*)d_in[1];
    const float* bq = (const float*)d_in[2];
    const float* Wk = (const float*)d_in[3];
    const float* bk = (const float*)d_in[4];
    const float* Wv = (const float*)d_in[5];
    const float* bv = (const float*)d_in[6];
    const float* Wo = (const float*)d_in[7];
    const float* bo = (const float*)d_in[8];

    const size_t E = (size_t)MROWS * D_MODEL;
    ushort_t* xb    = (ushort_t*)d_ws;               // [4096][1024] bf16
    ushort_t* WtQKV = xb + E;                        // [3072][1024] bf16
    ushort_t* WtO   = WtQKV + 3 * (size_t)D_MODEL * KDIM;
    ushort_t* Qb    = WtO + (size_t)D_MODEL * KDIM;  // [b,h,s,d] bf16 (pre-scaled)
    ushort_t* Kb    = Qb + E;                        // [b,h,s,d] bf16
    ushort_t* Vb    = Kb + E;                        // [b,h,d,s] bf16 (transposed)
    ushort_t* Hb    = Vb + E;                        // [4096][1024] bf16

    cvt_all<<<dim3(32, 32, 5), 256, 0, stream>>>(x, Wq, Wk, Wv, Wo, xb, WtQKV, WtO);
    gemm_qkv<<<dim3(24, 32), 256, 0, stream>>>(xb, WtQKV, bq, bk, bv, Qb, Kb, Vb);
    attn_mfma<<<dim3(512), 256, 0, stream>>>(Qb, Kb, Vb, Hb);
    gemm_o<<<dim3(16, 32), 128, 0, stream>>>(Hb, WtO, bo, (float*)d_out);
}

// Round 12
// 179.178 us; speedup vs baseline: 2.1412x; 1.0562x over previous
//
#include <hip/hip_runtime.h>
#include <hip/hip_bf16.h>
#include <cmath>

#define D_MODEL 1024
#define NHEADS 16
#define HDIM 64
#define BATCH 2
#define SEQ 2048
#define MROWS (BATCH*SEQ)   // 4096
#define KDIM 1024

typedef unsigned short ushort_t;
typedef unsigned int uint32;
typedef __attribute__((ext_vector_type(8))) short short8;
typedef __attribute__((ext_vector_type(4))) short short4b;
typedef __attribute__((ext_vector_type(4))) float floatx4;

#define QSCALE 0.1803368801111204f   /* 0.125 * log2(e): scores land in exp2 domain */
#define EXP2F(x) __builtin_amdgcn_exp2f(x)

__device__ __forceinline__ ushort_t f2bf(float x) {
    union { float f; uint32 u; } v; v.f = x;
    uint32 r = v.u + 0x7FFFu + ((v.u >> 16) & 1u);
    return (ushort_t)(r >> 16);
}

__device__ __forceinline__ uint32 pkbf(float a, float b) {
    union { __hip_bfloat162 h2; uint32 u; } v;
    v.h2 = __float22bfloat162_rn(make_float2(a, b));
    return v.u;
}

__device__ __forceinline__ void glds16(const void* g, void* l) {
    __builtin_amdgcn_global_load_lds(
        (const __attribute__((address_space(1))) void*)g,
        (__attribute__((address_space(3))) void*)l, 16, 0, 0);
}

// ---------------- fused conversions: z<4 -> W transpose, z==4 -> x cvt ----------------
__global__ __launch_bounds__(256)
void cvt_all(const float* __restrict__ x, const float* __restrict__ W0,
             const float* __restrict__ W1, const float* __restrict__ W2,
             const float* __restrict__ W3, ushort_t* __restrict__ xb,
             ushort_t* __restrict__ WtQKV, ushort_t* __restrict__ WtO)
{
    const int z = blockIdx.z;
    if (z == 4) {
        size_t idx = ((size_t)blockIdx.y * 32 + blockIdx.x) * 256 + threadIdx.x;
        #pragma unroll
        for (int l = 0; l < 4; ++l) {
            size_t i = ((size_t)l * 262144 + idx) * 4;
            float4 v = *(const float4*)(x + i);
            uint2 o;
            o.x = pkbf(v.x, v.y);
            o.y = pkbf(v.z, v.w);
            *(uint2*)(xb + i) = o;
        }
        return;
    }
    __shared__ float tl[32][33];
    const float* W = (z == 0) ? W0 : (z == 1) ? W1 : (z == 2) ? W2 : W3;
    ushort_t* out = (z < 3) ? (WtQKV + (size_t)z * D_MODEL * KDIM) : WtO;
    const int k0 = blockIdx.x * 32, n0 = blockIdx.y * 32;
    const int tx = threadIdx.x & 31, ty = threadIdx.x >> 5;
    #pragma unroll
    for (int i = 0; i < 4; ++i)
        tl[ty + i * 8][tx] = W[(size_t)(k0 + ty + i * 8) * D_MODEL + n0 + tx];
    __syncthreads();
    #pragma unroll
    for (int i = 0; i < 4; ++i)
        out[(size_t)(n0 + ty + i * 8) * KDIM + k0 + tx] = f2bf(tl[tx][ty + i * 8]);
}

// ---------------- QKV GEMM v4: 128x64 tiles, 2 waves, 1536 blocks, T1 swizzle --------
// R11 lesson: at ~180 regs/wave (116 VGPR + 64 acc) only 2 waves/SIMD fit ->
// 4-wave blocks cap at 2 blocks/CU with lockstep barriers (50us, regression).
// v4 adds parallelism via more 2-wave BLOCKS instead: 128x64 tiles -> 1536
// blocks (gemm_o's proven structure + QKV epilogue). Residency 4 blocks/CU
// (8 waves) + refill (1536 > 1024 capacity, uniform work). Same per-fragment
// K-order -> bit-identical output. 64-wide n-tile never crosses a 1024
// boundary -> `which` logic unchanged.
__global__ __launch_bounds__(128, 2)
void gemm_qkv(const ushort_t* __restrict__ A, const ushort_t* __restrict__ Bt,
              const float* __restrict__ b0, const float* __restrict__ b1,
              const float* __restrict__ b2, ushort_t* __restrict__ Qb,
              ushort_t* __restrict__ Kb, ushort_t* __restrict__ Vb)
{
    __shared__ ushort_t As[128 * 64];   // 16 KB
    __shared__ ushort_t Bs[64 * 64];    //  8 KB

    const int tid = threadIdx.x;
    const int w = tid >> 6, lane = tid & 63;
    const int quad = lane >> 4, col = lane & 15;
    const int flat = blockIdx.y * 48 + blockIdx.x;    // dispatch order (x-fastest)
    const int xcd = flat & 7, ii = flat >> 3;         // ii in [0,192)
    const int nf = xcd * 192 + ii;                    // contiguous chunk per XCD
    const int m0 = (nf / 48) * 128, n0 = (nf % 48) * 64;

    floatx4 zero = {0.f, 0.f, 0.f, 0.f};
    floatx4 acc[4][4];
    #pragma unroll
    for (int i = 0; i < 4; ++i)
        #pragma unroll
        for (int j = 0; j < 4; ++j) acc[i][j] = zero;

    #pragma unroll 1
    for (int k0 = 0; k0 < KDIM; k0 += 64) {
        #pragma unroll
        for (int i = 0; i < 8; ++i) {
            int c = i * 128 + tid;
            int row = c >> 3;
            int kc = (c & 7) ^ (row & 7);
            glds16(A + (size_t)(m0 + row) * KDIM + k0 + kc * 8, As + (i * 128 + w * 64) * 8);
        }
        #pragma unroll
        for (int i = 0; i < 4; ++i) {
            int c = i * 128 + tid;
            int row = c >> 3;
            int kc = (c & 7) ^ (row & 7);
            glds16(Bt + (size_t)(n0 + row) * KDIM + k0 + kc * 8, Bs + (i * 128 + w * 64) * 8);
        }
        __syncthreads();
        #pragma unroll
        for (int ks = 0; ks < 2; ++ks) {
            short8 af[4], bfr[4];
            const int kc = ks * 4 + quad;
            #pragma unroll
            for (int mt = 0; mt < 4; ++mt) {
                int r = w * 64 + mt * 16 + col;
                af[mt] = *(const short8*)(As + ((size_t)r * 8 + (kc ^ (r & 7))) * 8);
            }
            #pragma unroll
            for (int nt = 0; nt < 4; ++nt) {
                int r = nt * 16 + col;
                bfr[nt] = *(const short8*)(Bs + ((size_t)r * 8 + (kc ^ (r & 7))) * 8);
            }
            #pragma unroll
            for (int mt = 0; mt < 4; ++mt)
                #pragma unroll
                for (int nt = 0; nt < 4; ++nt)
                    acc[mt][nt] = __builtin_amdgcn_mfma_f32_16x16x32_bf16(
                        af[mt], bfr[nt], acc[mt][nt], 0, 0, 0);
        }
        __syncthreads();
    }

    const int which = n0 >> 10;
    const float* bp = (which == 0) ? b0 : (which == 1) ? b1 : b2;
    if (which < 2) {
        ushort_t* outp = (which == 0) ? Qb : Kb;
        const float scl = (which == 0) ? QSCALE : 1.0f;
        #pragma unroll
        for (int mt = 0; mt < 4; ++mt)
            #pragma unroll
            for (int nt = 0; nt < 4; ++nt) {
                int nn = (n0 + nt * 16 + col) & 1023;
                float bb = bp[nn];
                int h = nn >> 6, d = nn & 63;
                #pragma unroll
                for (int r = 0; r < 4; ++r) {
                    int m = m0 + w * 64 + mt * 16 + quad * 4 + r;
                    int b = m >> 11, s = m & 2047;
                    outp[((size_t)(b * NHEADS + h) * SEQ + s) * HDIM + d] =
                        f2bf((acc[mt][nt][r] + bb) * scl);
                }
            }
    } else {
        // V -> [b,h,d,s] transposed, packed 8B stores
        #pragma unroll
        for (int mt = 0; mt < 4; ++mt)
            #pragma unroll
            for (int nt = 0; nt < 4; ++nt) {
                int nn = (n0 + nt * 16 + col) & 1023;
                float bb = bp[nn];
                int h = nn >> 6, d = nn & 63;
                int mb = m0 + w * 64 + mt * 16 + quad * 4;
                int b = mb >> 11, s = mb & 2047;
                uint2 pw;
                pw.x = pkbf(acc[mt][nt][0] + bb, acc[mt][nt][1] + bb);
                pw.y = pkbf(acc[mt][nt][2] + bb, acc[mt][nt][3] + bb);
                *(uint2*)(Vb + ((size_t)(b * NHEADS + h) * HDIM + d) * SEQ + s) = pw;
            }
    }
}

// ---------------- out-projection GEMM v2 + T1 XCD-chunked block swizzle --------------
__global__ __launch_bounds__(128, 2)
void gemm_o(const ushort_t* __restrict__ A, const ushort_t* __restrict__ Bt,
            const float* __restrict__ b0, float* __restrict__ Cf)
{
    __shared__ ushort_t As[128 * 64];   // 16 KB
    __shared__ ushort_t Bs[64 * 64];    //  8 KB

    const int tid = threadIdx.x;
    const int w = tid >> 6, lane = tid & 63;
    const int quad = lane >> 4, col = lane & 15;
    const int flat = blockIdx.y * 16 + blockIdx.x;    // dispatch order (x-fastest)
    const int xcd = flat & 7, ii = flat >> 3;         // ii in [0,64)
    const int nf = xcd * 64 + ii;                     // contiguous chunk per XCD
    const int m0 = (nf / 16) * 128, n0 = (nf % 16) * 64;

    floatx4 zero = {0.f, 0.f, 0.f, 0.f};
    floatx4 acc[4][4];
    #pragma unroll
    for (int i = 0; i < 4; ++i)
        #pragma unroll
        for (int j = 0; j < 4; ++j) acc[i][j] = zero;

    #pragma unroll 1
    for (int k0 = 0; k0 < KDIM; k0 += 64) {
        #pragma unroll
        for (int i = 0; i < 8; ++i) {
            int c = i * 128 + tid;
            int row = c >> 3;
            int kc = (c & 7) ^ (row & 7);
            glds16(A + (size_t)(m0 + row) * KDIM + k0 + kc * 8, As + (i * 128 + w * 64) * 8);
        }
        #pragma unroll
        for (int i = 0; i < 4; ++i) {
            int c = i * 128 + tid;
            int row = c >> 3;
            int kc = (c & 7) ^ (row & 7);
            glds16(Bt + (size_t)(n0 + row) * KDIM + k0 + kc * 8, Bs + (i * 128 + w * 64) * 8);
        }
        __syncthreads();
        #pragma unroll
        for (int ks = 0; ks < 2; ++ks) {
            short8 af[4], bfr[4];
            const int kc = ks * 4 + quad;
            #pragma unroll
            for (int mt = 0; mt < 4; ++mt) {
                int r = w * 64 + mt * 16 + col;
                af[mt] = *(const short8*)(As + ((size_t)r * 8 + (kc ^ (r & 7))) * 8);
            }
            #pragma unroll
            for (int nt = 0; nt < 4; ++nt) {
                int r = nt * 16 + col;
                bfr[nt] = *(const short8*)(Bs + ((size_t)r * 8 + (kc ^ (r & 7))) * 8);
            }
            #pragma unroll
            for (int mt = 0; mt < 4; ++mt)
                #pragma unroll
                for (int nt = 0; nt < 4; ++nt)
                    acc[mt][nt] = __builtin_amdgcn_mfma_f32_16x16x32_bf16(
                        af[mt], bfr[nt], acc[mt][nt], 0, 0, 0);
        }
        __syncthreads();
    }

    #pragma unroll
    for (int mt = 0; mt < 4; ++mt)
        #pragma unroll
        for (int nt = 0; nt < 4; ++nt) {
            int n = n0 + nt * 16 + col;
            float bb = b0[n];
            #pragma unroll
            for (int r = 0; r < 4; ++r) {
                int m = m0 + w * 64 + mt * 16 + quad * 4 + r;
                Cf[(size_t)m * D_MODEL + n] = acc[mt][nt][r] + bb;
            }
        }
}

// ---------------- flash causal attention v14: pipelined QK^T, 3-buffer LDS ----------
__global__ __launch_bounds__(256)
void attn_mfma(const ushort_t* __restrict__ Q, const ushort_t* __restrict__ K,
               const ushort_t* __restrict__ Vt, ushort_t* __restrict__ H)
{
    __shared__ __align__(16) float smemf[16640];           // 65 KB
    ushort_t* Qs  = (ushort_t*)smemf;                      // [64][64]
    ushort_t* Ksb = (ushort_t*)(smemf + 2048);             // 3 x [64*64]
    ushort_t* Vsb = (ushort_t*)(smemf + 8192);             // 3 x [64*64]
    float* Ored = smemf;                                   // [4][64q][64d] swizzled
    float* Lred = smemf + 16384;                           // [4][64]

    const int tid = threadIdx.x;
    const int w = tid >> 6, lane = tid & 63;
    const int quad = lane >> 4, col = lane & 15;
    const int blk = blockIdx.x;                       // 0..511
    const int bh = (blk & 7) * 4 + ((blk >> 3) & 3);  // XCD-grouped
    const int pair = blk >> 5;                        // 0..15
    const size_t base = (size_t)bh * SEQ * HDIM;
    const ushort_t* Kb = K + base;
    const ushort_t* Vb = Vt + base;
    const int b = bh >> 4, h = bh & 15;

    const int c0 = (w * 2 + 0) * 64 + lane;
    const int c1 = (w * 2 + 1) * 64 + lane;
    const int r0 = c0 >> 3, o0 = ((c0 & 7) ^ (r0 & 7)) * 8;
    const int r1 = c1 >> 3, o1 = ((c1 & 7) ^ (r1 & 7)) * 8;

    const int rk = w * 16 + col;          // wave's K row (kpos slice base + col)
    const floatx4 zero = {0.f, 0.f, 0.f, 0.f};

    #pragma unroll 1
    for (int pi = 0; pi < 2; ++pi) {
        const int qt = pi ? pair : 31 - pair;
        const int q0 = qt * 64;
        const int nt = qt + 1;

        __syncthreads();     // previous q-tile's epilogue readers of Ored done
        #pragma unroll
        for (int i = 0; i < 2; ++i) {
            int c = (w * 2 + i) * 64 + lane;
            int row = c >> 3, kc = (c & 7) ^ (row & 7);
            glds16(Q + base + (size_t)(q0 + row) * HDIM + kc * 8, Qs + (w * 2 + i) * 512);
        }
        glds16(Kb + (size_t)r0 * HDIM + o0, Ksb + (w * 2 + 0) * 512);
        glds16(Kb + (size_t)r1 * HDIM + o1, Ksb + (w * 2 + 1) * 512);
        glds16(Vb + (size_t)r0 * SEQ + o0,  Vsb + (w * 2 + 0) * 512);
        glds16(Vb + (size_t)r1 * SEQ + o1,  Vsb + (w * 2 + 1) * 512);
        if (nt > 1) {
            glds16(Kb + (size_t)(64 + r0) * HDIM + o0, Ksb + 4096 + (w * 2 + 0) * 512);
            glds16(Kb + (size_t)(64 + r1) * HDIM + o1, Ksb + 4096 + (w * 2 + 1) * 512);
            glds16(Vb + (size_t)r0 * SEQ + 64 + o0,    Vsb + 4096 + (w * 2 + 0) * 512);
            glds16(Vb + (size_t)r1 * SEQ + 64 + o1,    Vsb + 4096 + (w * 2 + 1) * 512);
        }
        __syncthreads();     // Qs + buf0 + buf1 ready

        short8 bq[4][2];
        #pragma unroll
        for (int qb = 0; qb < 4; ++qb)
            #pragma unroll
            for (int ks = 0; ks < 2; ++ks) {
                int rq = qb * 16 + col;
                int kc = ks * 4 + quad;
                bq[qb][ks] = *(const short8*)(Qs + ((size_t)rq * 8 + (kc ^ (rq & 7))) * 8);
            }

        floatx4 o_[4][4];
        #pragma unroll
        for (int i = 0; i < 4; ++i)
            #pragma unroll
            for (int j = 0; j < 4; ++j) o_[i][j] = zero;
        float lq[4] = {0.f, 0.f, 0.f, 0.f};

        ushort_t* Kcur = Ksb;            ushort_t* Vcur = Vsb;
        ushort_t* Knxt = Ksb + 4096;     ushort_t* Vnxt = Vsb + 4096;
        ushort_t* Kstg = Ksb + 8192;     ushort_t* Vstg = Vsb + 8192;

        floatx4 scA[4];
        #pragma unroll
        for (int qb = 0; qb < 4; ++qb) scA[qb] = zero;
        __builtin_amdgcn_s_setprio(1);
        #pragma unroll
        for (int ks = 0; ks < 2; ++ks) {
            const int kc = ks * 4 + quad;
            short8 ak = *(const short8*)(Kcur + ((size_t)rk * 8 + (kc ^ (rk & 7))) * 8);
            #pragma unroll
            for (int qb = 0; qb < 4; ++qb)
                scA[qb] = __builtin_amdgcn_mfma_f32_16x16x32_bf16(
                    ak, bq[qb][ks], scA[qb], 0, 0, 0);
        }
        __builtin_amdgcn_s_setprio(0);

        #pragma unroll 1
        for (int t = 0; t < nt; ++t) {
            if (t + 2 < nt) {            // async stage t+2 into stg buffer
                const int k0n = (t + 2) * 64;
                glds16(Kb + (size_t)(k0n + r0) * HDIM + o0, Kstg + (w * 2 + 0) * 512);
                glds16(Kb + (size_t)(k0n + r1) * HDIM + o1, Kstg + (w * 2 + 1) * 512);
                glds16(Vb + (size_t)r0 * SEQ + k0n + o0,    Vstg + (w * 2 + 0) * 512);
                glds16(Vb + (size_t)r1 * SEQ + k0n + o1,    Vstg + (w * 2 + 1) * 512);
            }

            if (t == nt - 1) {
                #pragma unroll
                for (int qb = 0; qb < 4; ++qb)
                    #pragma unroll
                    for (int r = 0; r < 4; ++r)
                        if (w * 16 + quad * 4 + r > qb * 16 + col) scA[qb][r] = -INFINITY;
            }

            short4b bp[4];
            #pragma unroll
            for (int qb = 0; qb < 4; ++qb) {
                float p0 = EXP2F(scA[qb][0]);
                float p1 = EXP2F(scA[qb][1]);
                float p2 = EXP2F(scA[qb][2]);
                float p3 = EXP2F(scA[qb][3]);
                lq[qb] += (p0 + p1) + (p2 + p3);
                union { uint2 u; short4b s; } pv;
                pv.u.x = pkbf(p0, p1);
                pv.u.y = pkbf(p2, p3);
                bp[qb] = pv.s;
            }

            floatx4 scB[4];
            if (t + 1 < nt) {
                #pragma unroll
                for (int qb = 0; qb < 4; ++qb) scB[qb] = zero;
                __builtin_amdgcn_s_setprio(1);
                #pragma unroll
                for (int ks = 0; ks < 2; ++ks) {
                    const int kc = ks * 4 + quad;
                    short8 ak = *(const short8*)(Knxt + ((size_t)rk * 8 + (kc ^ (rk & 7))) * 8);
                    #pragma unroll
                    for (int qb = 0; qb < 4; ++qb)
                        scB[qb] = __builtin_amdgcn_mfma_f32_16x16x32_bf16(
                            ak, bq[qb][ks], scB[qb], 0, 0, 0);
                }
                __builtin_amdgcn_s_setprio(0);
            }

            const int cc = 2 * w + (quad >> 1);    // 8-elem chunk of elems w*16+quad*4
            const int sub = (quad & 1) * 4;
            __builtin_amdgcn_s_setprio(1);
            #pragma unroll
            for (int db = 0; db < 4; ++db) {
                int rv = db * 16 + col;
                short4b av = *(const short4b*)(Vcur + ((size_t)rv * 8 + (cc ^ (rv & 7))) * 8 + sub);
                #pragma unroll
                for (int qb = 0; qb < 4; ++qb)
                    o_[db][qb] = __builtin_amdgcn_mfma_f32_16x16x16bf16_1k(
                        av, bp[qb], o_[db][qb], 0, 0, 0);
            }
            __builtin_amdgcn_s_setprio(0);

            __syncthreads();   // publish stg buffer + fence buffer rotation

            ushort_t* tk = Kcur; Kcur = Knxt; Knxt = Kstg; Kstg = tk;
            ushort_t* tv = Vcur; Vcur = Vnxt; Vnxt = Vstg; Vstg = tv;
            if (t + 1 < nt) {
                #pragma unroll
                for (int qb = 0; qb < 4; ++qb) scA[qb] = scB[qb];
            }
        }

        #pragma unroll
        for (int qb = 0; qb < 4; ++qb) {
            lq[qb] += __shfl_xor(lq[qb], 16);
            lq[qb] += __shfl_xor(lq[qb], 32);
        }
        if (quad == 0) {
            #pragma unroll
            for (int qb = 0; qb < 4; ++qb) Lred[w * 64 + qb * 16 + col] = lq[qb];
        }
        {
            float* myreg = Ored + w * 4096;
            #pragma unroll
            for (int db = 0; db < 4; ++db)
                #pragma unroll
                for (int qb = 0; qb < 4; ++qb) {
                    int q = qb * 16 + col;
                    int swch = (db * 4 + quad) ^ col;
                    *(floatx4*)(myreg + q * 64 + swch * 4) = o_[db][qb];
                }
        }
        __syncthreads();

        {
            const int qloc = w * 16 + (lane >> 2);
            float lsum = Lred[qloc] + Lred[64 + qloc] + Lred[128 + qloc] + Lred[192 + qloc];
            float linv = 1.f / lsum;
            const int dc0 = (lane & 3) * 4;        // 4 d-chunks of 4 floats
            floatx4 acc[4];
            #pragma unroll
            for (int j = 0; j < 4; ++j) {
                int swch = (dc0 + j) ^ (qloc & 15);
                const float* p = Ored + (size_t)qloc * 64 + swch * 4;
                floatx4 a = *(const floatx4*)p;
                a += *(const floatx4*)(p + 4096);
                a += *(const floatx4*)(p + 8192);
                a += *(const floatx4*)(p + 12288);
                acc[j] = a;
            }
            const size_t rowb = ((size_t)(b * SEQ + q0 + qloc)) * D_MODEL + h * HDIM + dc0 * 4;
            uint4 u0, u1;
            u0.x = pkbf(acc[0][0] * linv, acc[0][1] * linv);
            u0.y = pkbf(acc[0][2] * linv, acc[0][3] * linv);
            u0.z = pkbf(acc[1][0] * linv, acc[1][1] * linv);
            u0.w = pkbf(acc[1][2] * linv, acc[1][3] * linv);
            u1.x = pkbf(acc[2][0] * linv, acc[2][1] * linv);
            u1.y = pkbf(acc[2][2] * linv, acc[2][3] * linv);
            u1.z = pkbf(acc[3][0] * linv, acc[3][1] * linv);
            u1.w = pkbf(acc[3][2] * linv, acc[3][3] * linv);
            *(uint4*)(H + rowb) = u0;
            *(uint4*)(H + rowb + 8) = u1;
        }
    }
}

extern "C" void kernel_launch(void* const* d_in, const int* in_sizes, int n_in,
                              void* d_out, int out_size, void* d_ws, size_t ws_size,
                              hipStream_t stream)
{
    (void)in_sizes; (void)n_in; (void)out_size; (void)ws_size;
    const float* x  = (const float*)d_in[0];
    const float* Wq = (const float*)d_in[1];
    const float* bq = (const float*)d_in[2];
    const float* Wk = (const float*)d_in[3];
    const float* bk = (const float*)d_in[4];
    const float* Wv = (const float*)d_in[5];
    const float* bv = (const float*)d_in[6];
    const float* Wo = (const float*)d_in[7];
    const float* bo = (const float*)d_in[8];

    const size_t E = (size_t)MROWS * D_MODEL;
    ushort_t* xb    = (ushort_t*)d_ws;               // [4096][1024] bf16
    ushort_t* WtQKV = xb + E;                        // [3072][1024] bf16
    ushort_t* WtO   = WtQKV + 3 * (size_t)D_MODEL * KDIM;
    ushort_t* Qb    = WtO + (size_t)D_MODEL * KDIM;  // [b,h,s,d] bf16 (pre-scaled)
    ushort_t* Kb    = Qb + E;                        // [b,h,s,d] bf16
    ushort_t* Vb    = Kb + E;                        // [b,h,d,s] bf16 (transposed)
    ushort_t* Hb    = Vb + E;                        // [4096][1024] bf16

    cvt_all<<<dim3(32, 32, 5), 256, 0, stream>>>(x, Wq, Wk, Wv, Wo, xb, WtQKV, WtO);
    gemm_qkv<<<dim3(48, 32), 128, 0, stream>>>(xb, WtQKV, bq, bk, bv, Qb, Kb, Vb);
    attn_mfma<<<dim3(512), 256, 0, stream>>>(Qb, Kb, Vb, Hb);
    gemm_o<<<dim3(16, 32), 128, 0, stream>>>(Hb, WtO, bo, (float*)d_out);
}

// Round 13
// 173.364 us; speedup vs baseline: 2.2131x; 1.0335x over previous
//
#include <hip/hip_runtime.h>
#include <hip/hip_bf16.h>
#include <cmath>

#define D_MODEL 1024
#define NHEADS 16
#define HDIM 64
#define BATCH 2
#define SEQ 2048
#define MROWS (BATCH*SEQ)   // 4096
#define KDIM 1024

typedef unsigned short ushort_t;
typedef unsigned int uint32;
typedef __attribute__((ext_vector_type(8))) short short8;
typedef __attribute__((ext_vector_type(4))) short short4b;
typedef __attribute__((ext_vector_type(4))) float floatx4;

#define QSCALE 0.1803368801111204f   /* 0.125 * log2(e): scores land in exp2 domain */
#define EXP2F(x) __builtin_amdgcn_exp2f(x)

__device__ __forceinline__ ushort_t f2bf(float x) {
    union { float f; uint32 u; } v; v.f = x;
    uint32 r = v.u + 0x7FFFu + ((v.u >> 16) & 1u);
    return (ushort_t)(r >> 16);
}

__device__ __forceinline__ uint32 pkbf(float a, float b) {
    union { __hip_bfloat162 h2; uint32 u; } v;
    v.h2 = __float22bfloat162_rn(make_float2(a, b));
    return v.u;
}

__device__ __forceinline__ void glds16(const void* g, void* l) {
    __builtin_amdgcn_global_load_lds(
        (const __attribute__((address_space(1))) void*)g,
        (__attribute__((address_space(3))) void*)l, 16, 0, 0);
}

// ---------------- fused conversions: z<4 -> W transpose, z==4 -> x cvt ----------------
__global__ __launch_bounds__(256)
void cvt_all(const float* __restrict__ x, const float* __restrict__ W0,
             const float* __restrict__ W1, const float* __restrict__ W2,
             const float* __restrict__ W3, ushort_t* __restrict__ xb,
             ushort_t* __restrict__ WtQKV, ushort_t* __restrict__ WtO)
{
    const int z = blockIdx.z;
    if (z == 4) {
        size_t idx = ((size_t)blockIdx.y * 32 + blockIdx.x) * 256 + threadIdx.x;
        #pragma unroll
        for (int l = 0; l < 4; ++l) {
            size_t i = ((size_t)l * 262144 + idx) * 4;
            float4 v = *(const float4*)(x + i);
            uint2 o;
            o.x = pkbf(v.x, v.y);
            o.y = pkbf(v.z, v.w);
            *(uint2*)(xb + i) = o;
        }
        return;
    }
    __shared__ float tl[32][33];
    const float* W = (z == 0) ? W0 : (z == 1) ? W1 : (z == 2) ? W2 : W3;
    ushort_t* out = (z < 3) ? (WtQKV + (size_t)z * D_MODEL * KDIM) : WtO;
    const int k0 = blockIdx.x * 32, n0 = blockIdx.y * 32;
    const int tx = threadIdx.x & 31, ty = threadIdx.x >> 5;
    #pragma unroll
    for (int i = 0; i < 4; ++i)
        tl[ty + i * 8][tx] = W[(size_t)(k0 + ty + i * 8) * D_MODEL + n0 + tx];
    __syncthreads();
    #pragma unroll
    for (int i = 0; i < 4; ++i)
        out[(size_t)(n0 + ty + i * 8) * KDIM + k0 + tx] = f2bf(tl[tx][ty + i * 8]);
}

// ---------------- QKV GEMM (R11 proven) + T1 XCD-chunked block swizzle ----------------
// 2-wave 128x128 tile: the measured local optimum for this short-K (16-step)
// GEMM. 4-wave blocks (R11: 50us) and 128x64 tiles (R12: ~44us) both regress.
__global__ __launch_bounds__(128, 2)
void gemm_qkv(const ushort_t* __restrict__ A, const ushort_t* __restrict__ Bt,
              const float* __restrict__ b0, const float* __restrict__ b1,
              const float* __restrict__ b2, ushort_t* __restrict__ Qb,
              ushort_t* __restrict__ Kb, ushort_t* __restrict__ Vb)
{
    __shared__ ushort_t As[128 * 64];   // 16 KB
    __shared__ ushort_t Bs[128 * 64];   // 16 KB

    const int tid = threadIdx.x;
    const int w = tid >> 6, lane = tid & 63;
    const int quad = lane >> 4, col = lane & 15;
    const int flat = blockIdx.y * 24 + blockIdx.x;    // dispatch order (x-fastest)
    const int xcd = flat & 7, ii = flat >> 3;         // ii in [0,96)
    const int nf = xcd * 96 + ii;                     // contiguous chunk per XCD
    const int m0 = (nf / 24) * 128, n0 = (nf % 24) * 128;

    floatx4 zero = {0.f, 0.f, 0.f, 0.f};
    floatx4 acc[4][8];
    #pragma unroll
    for (int i = 0; i < 4; ++i)
        #pragma unroll
        for (int j = 0; j < 8; ++j) acc[i][j] = zero;

    #pragma unroll 1
    for (int k0 = 0; k0 < KDIM; k0 += 64) {
        #pragma unroll
        for (int i = 0; i < 8; ++i) {
            int c = i * 128 + tid;
            int row = c >> 3;
            int kc = (c & 7) ^ (row & 7);
            glds16(A  + (size_t)(m0 + row) * KDIM + k0 + kc * 8, As + (i * 128 + w * 64) * 8);
            glds16(Bt + (size_t)(n0 + row) * KDIM + k0 + kc * 8, Bs + (i * 128 + w * 64) * 8);
        }
        __syncthreads();
        #pragma unroll
        for (int ks = 0; ks < 2; ++ks) {
            short8 af[4], bfr[8];
            const int kc = ks * 4 + quad;
            #pragma unroll
            for (int mt = 0; mt < 4; ++mt) {
                int r = w * 64 + mt * 16 + col;
                af[mt] = *(const short8*)(As + ((size_t)r * 8 + (kc ^ (r & 7))) * 8);
            }
            #pragma unroll
            for (int nt = 0; nt < 8; ++nt) {
                int r = nt * 16 + col;
                bfr[nt] = *(const short8*)(Bs + ((size_t)r * 8 + (kc ^ (r & 7))) * 8);
            }
            #pragma unroll
            for (int mt = 0; mt < 4; ++mt)
                #pragma unroll
                for (int nt = 0; nt < 8; ++nt)
                    acc[mt][nt] = __builtin_amdgcn_mfma_f32_16x16x32_bf16(
                        af[mt], bfr[nt], acc[mt][nt], 0, 0, 0);
        }
        __syncthreads();
    }

    const int which = n0 >> 10;
    const float* bp = (which == 0) ? b0 : (which == 1) ? b1 : b2;
    if (which < 2) {
        ushort_t* outp = (which == 0) ? Qb : Kb;
        const float scl = (which == 0) ? QSCALE : 1.0f;
        #pragma unroll
        for (int mt = 0; mt < 4; ++mt)
            #pragma unroll
            for (int nt = 0; nt < 8; ++nt) {
                int nn = (n0 + nt * 16 + col) & 1023;
                float bb = bp[nn];
                int h = nn >> 6, d = nn & 63;
                #pragma unroll
                for (int r = 0; r < 4; ++r) {
                    int m = m0 + w * 64 + mt * 16 + quad * 4 + r;
                    int b = m >> 11, s = m & 2047;
                    outp[((size_t)(b * NHEADS + h) * SEQ + s) * HDIM + d] =
                        f2bf((acc[mt][nt][r] + bb) * scl);
                }
            }
    } else {
        // V -> [b,h,d,s] transposed, packed 8B stores
        #pragma unroll
        for (int mt = 0; mt < 4; ++mt)
            #pragma unroll
            for (int nt = 0; nt < 8; ++nt) {
                int nn = (n0 + nt * 16 + col) & 1023;
                float bb = bp[nn];
                int h = nn >> 6, d = nn & 63;
                int mb = m0 + w * 64 + mt * 16 + quad * 4;
                int b = mb >> 11, s = mb & 2047;
                uint2 pw;
                pw.x = pkbf(acc[mt][nt][0] + bb, acc[mt][nt][1] + bb);
                pw.y = pkbf(acc[mt][nt][2] + bb, acc[mt][nt][3] + bb);
                *(uint2*)(Vb + ((size_t)(b * NHEADS + h) * HDIM + d) * SEQ + s) = pw;
            }
    }
}

// ---------------- out-projection GEMM v2 + T1 XCD-chunked block swizzle --------------
__global__ __launch_bounds__(128, 2)
void gemm_o(const ushort_t* __restrict__ A, const ushort_t* __restrict__ Bt,
            const float* __restrict__ b0, float* __restrict__ Cf)
{
    __shared__ ushort_t As[128 * 64];   // 16 KB
    __shared__ ushort_t Bs[64 * 64];    //  8 KB

    const int tid = threadIdx.x;
    const int w = tid >> 6, lane = tid & 63;
    const int quad = lane >> 4, col = lane & 15;
    const int flat = blockIdx.y * 16 + blockIdx.x;    // dispatch order (x-fastest)
    const int xcd = flat & 7, ii = flat >> 3;         // ii in [0,64)
    const int nf = xcd * 64 + ii;                     // contiguous chunk per XCD
    const int m0 = (nf / 16) * 128, n0 = (nf % 16) * 64;

    floatx4 zero = {0.f, 0.f, 0.f, 0.f};
    floatx4 acc[4][4];
    #pragma unroll
    for (int i = 0; i < 4; ++i)
        #pragma unroll
        for (int j = 0; j < 4; ++j) acc[i][j] = zero;

    #pragma unroll 1
    for (int k0 = 0; k0 < KDIM; k0 += 64) {
        #pragma unroll
        for (int i = 0; i < 8; ++i) {
            int c = i * 128 + tid;
            int row = c >> 3;
            int kc = (c & 7) ^ (row & 7);
            glds16(A + (size_t)(m0 + row) * KDIM + k0 + kc * 8, As + (i * 128 + w * 64) * 8);
        }
        #pragma unroll
        for (int i = 0; i < 4; ++i) {
            int c = i * 128 + tid;
            int row = c >> 3;
            int kc = (c & 7) ^ (row & 7);
            glds16(Bt + (size_t)(n0 + row) * KDIM + k0 + kc * 8, Bs + (i * 128 + w * 64) * 8);
        }
        __syncthreads();
        #pragma unroll
        for (int ks = 0; ks < 2; ++ks) {
            short8 af[4], bfr[4];
            const int kc = ks * 4 + quad;
            #pragma unroll
            for (int mt = 0; mt < 4; ++mt) {
                int r = w * 64 + mt * 16 + col;
                af[mt] = *(const short8*)(As + ((size_t)r * 8 + (kc ^ (r & 7))) * 8);
            }
            #pragma unroll
            for (int nt = 0; nt < 4; ++nt) {
                int r = nt * 16 + col;
                bfr[nt] = *(const short8*)(Bs + ((size_t)r * 8 + (kc ^ (r & 7))) * 8);
            }
            #pragma unroll
            for (int mt = 0; mt < 4; ++mt)
                #pragma unroll
                for (int nt = 0; nt < 4; ++nt)
                    acc[mt][nt] = __builtin_amdgcn_mfma_f32_16x16x32_bf16(
                        af[mt], bfr[nt], acc[mt][nt], 0, 0, 0);
        }
        __syncthreads();
    }

    #pragma unroll
    for (int mt = 0; mt < 4; ++mt)
        #pragma unroll
        for (int nt = 0; nt < 4; ++nt) {
            int n = n0 + nt * 16 + col;
            float bb = b0[n];
            #pragma unroll
            for (int r = 0; r < 4; ++r) {
                int m = m0 + w * 64 + mt * 16 + quad * 4 + r;
                Cf[(size_t)m * D_MODEL + n] = acc[mt][nt][r] + bb;
            }
        }
}

// ---------------- flash causal attention v14: pipelined QK^T, 3-buffer LDS ----------
// QK^T(t+1) on the matrix pipe overlaps softmax(t)'s exp2 on the trans/VALU
// pipe; triple-buffered K/V; bit-identical math/accumulation order.
__global__ __launch_bounds__(256)
void attn_mfma(const ushort_t* __restrict__ Q, const ushort_t* __restrict__ K,
               const ushort_t* __restrict__ Vt, ushort_t* __restrict__ H)
{
    __shared__ __align__(16) float smemf[16640];           // 65 KB
    ushort_t* Qs  = (ushort_t*)smemf;                      // [64][64]
    ushort_t* Ksb = (ushort_t*)(smemf + 2048);             // 3 x [64*64]
    ushort_t* Vsb = (ushort_t*)(smemf + 8192);             // 3 x [64*64]
    float* Ored = smemf;                                   // [4][64q][64d] swizzled
    float* Lred = smemf + 16384;                           // [4][64]

    const int tid = threadIdx.x;
    const int w = tid >> 6, lane = tid & 63;
    const int quad = lane >> 4, col = lane & 15;
    const int blk = blockIdx.x;                       // 0..511
    const int bh = (blk & 7) * 4 + ((blk >> 3) & 3);  // XCD-grouped
    const int pair = blk >> 5;                        // 0..15
    const size_t base = (size_t)bh * SEQ * HDIM;
    const ushort_t* Kb = K + base;
    const ushort_t* Vb = Vt + base;
    const int b = bh >> 4, h = bh & 15;

    const int c0 = (w * 2 + 0) * 64 + lane;
    const int c1 = (w * 2 + 1) * 64 + lane;
    const int r0 = c0 >> 3, o0 = ((c0 & 7) ^ (r0 & 7)) * 8;
    const int r1 = c1 >> 3, o1 = ((c1 & 7) ^ (r1 & 7)) * 8;

    const int rk = w * 16 + col;          // wave's K row (kpos slice base + col)
    const floatx4 zero = {0.f, 0.f, 0.f, 0.f};

    #pragma unroll 1
    for (int pi = 0; pi < 2; ++pi) {
        const int qt = pi ? pair : 31 - pair;
        const int q0 = qt * 64;
        const int nt = qt + 1;

        __syncthreads();     // previous q-tile's epilogue readers of Ored done
        #pragma unroll
        for (int i = 0; i < 2; ++i) {
            int c = (w * 2 + i) * 64 + lane;
            int row = c >> 3, kc = (c & 7) ^ (row & 7);
            glds16(Q + base + (size_t)(q0 + row) * HDIM + kc * 8, Qs + (w * 2 + i) * 512);
        }
        glds16(Kb + (size_t)r0 * HDIM + o0, Ksb + (w * 2 + 0) * 512);
        glds16(Kb + (size_t)r1 * HDIM + o1, Ksb + (w * 2 + 1) * 512);
        glds16(Vb + (size_t)r0 * SEQ + o0,  Vsb + (w * 2 + 0) * 512);
        glds16(Vb + (size_t)r1 * SEQ + o1,  Vsb + (w * 2 + 1) * 512);
        if (nt > 1) {
            glds16(Kb + (size_t)(64 + r0) * HDIM + o0, Ksb + 4096 + (w * 2 + 0) * 512);
            glds16(Kb + (size_t)(64 + r1) * HDIM + o1, Ksb + 4096 + (w * 2 + 1) * 512);
            glds16(Vb + (size_t)r0 * SEQ + 64 + o0,    Vsb + 4096 + (w * 2 + 0) * 512);
            glds16(Vb + (size_t)r1 * SEQ + 64 + o1,    Vsb + 4096 + (w * 2 + 1) * 512);
        }
        __syncthreads();     // Qs + buf0 + buf1 ready

        short8 bq[4][2];
        #pragma unroll
        for (int qb = 0; qb < 4; ++qb)
            #pragma unroll
            for (int ks = 0; ks < 2; ++ks) {
                int rq = qb * 16 + col;
                int kc = ks * 4 + quad;
                bq[qb][ks] = *(const short8*)(Qs + ((size_t)rq * 8 + (kc ^ (rq & 7))) * 8);
            }

        floatx4 o_[4][4];
        #pragma unroll
        for (int i = 0; i < 4; ++i)
            #pragma unroll
            for (int j = 0; j < 4; ++j) o_[i][j] = zero;
        float lq[4] = {0.f, 0.f, 0.f, 0.f};

        ushort_t* Kcur = Ksb;            ushort_t* Vcur = Vsb;
        ushort_t* Knxt = Ksb + 4096;     ushort_t* Vnxt = Vsb + 4096;
        ushort_t* Kstg = Ksb + 8192;     ushort_t* Vstg = Vsb + 8192;

        floatx4 scA[4];
        #pragma unroll
        for (int qb = 0; qb < 4; ++qb) scA[qb] = zero;
        __builtin_amdgcn_s_setprio(1);
        #pragma unroll
        for (int ks = 0; ks < 2; ++ks) {
            const int kc = ks * 4 + quad;
            short8 ak = *(const short8*)(Kcur + ((size_t)rk * 8 + (kc ^ (rk & 7))) * 8);
            #pragma unroll
            for (int qb = 0; qb < 4; ++qb)
                scA[qb] = __builtin_amdgcn_mfma_f32_16x16x32_bf16(
                    ak, bq[qb][ks], scA[qb], 0, 0, 0);
        }
        __builtin_amdgcn_s_setprio(0);

        #pragma unroll 1
        for (int t = 0; t < nt; ++t) {
            if (t + 2 < nt) {            // async stage t+2 into stg buffer
                const int k0n = (t + 2) * 64;
                glds16(Kb + (size_t)(k0n + r0) * HDIM + o0, Kstg + (w * 2 + 0) * 512);
                glds16(Kb + (size_t)(k0n + r1) * HDIM + o1, Kstg + (w * 2 + 1) * 512);
                glds16(Vb + (size_t)r0 * SEQ + k0n + o0,    Vstg + (w * 2 + 0) * 512);
                glds16(Vb + (size_t)r1 * SEQ + k0n + o1,    Vstg + (w * 2 + 1) * 512);
            }

            if (t == nt - 1) {
                #pragma unroll
                for (int qb = 0; qb < 4; ++qb)
                    #pragma unroll
                    for (int r = 0; r < 4; ++r)
                        if (w * 16 + quad * 4 + r > qb * 16 + col) scA[qb][r] = -INFINITY;
            }

            short4b bp[4];
            #pragma unroll
            for (int qb = 0; qb < 4; ++qb) {
                float p0 = EXP2F(scA[qb][0]);
                float p1 = EXP2F(scA[qb][1]);
                float p2 = EXP2F(scA[qb][2]);
                float p3 = EXP2F(scA[qb][3]);
                lq[qb] += (p0 + p1) + (p2 + p3);
                union { uint2 u; short4b s; } pv;
                pv.u.x = pkbf(p0, p1);
                pv.u.y = pkbf(p2, p3);
                bp[qb] = pv.s;
            }

            floatx4 scB[4];
            if (t + 1 < nt) {
                #pragma unroll
                for (int qb = 0; qb < 4; ++qb) scB[qb] = zero;
                __builtin_amdgcn_s_setprio(1);
                #pragma unroll
                for (int ks = 0; ks < 2; ++ks) {
                    const int kc = ks * 4 + quad;
                    short8 ak = *(const short8*)(Knxt + ((size_t)rk * 8 + (kc ^ (rk & 7))) * 8);
                    #pragma unroll
                    for (int qb = 0; qb < 4; ++qb)
                        scB[qb] = __builtin_amdgcn_mfma_f32_16x16x32_bf16(
                            ak, bq[qb][ks], scB[qb], 0, 0, 0);
                }
                __builtin_amdgcn_s_setprio(0);
            }

            const int cc = 2 * w + (quad >> 1);    // 8-elem chunk of elems w*16+quad*4
            const int sub = (quad & 1) * 4;
            __builtin_amdgcn_s_setprio(1);
            #pragma unroll
            for (int db = 0; db < 4; ++db) {
                int rv = db * 16 + col;
                short4b av = *(const short4b*)(Vcur + ((size_t)rv * 8 + (cc ^ (rv & 7))) * 8 + sub);
                #pragma unroll
                for (int qb = 0; qb < 4; ++qb)
                    o_[db][qb] = __builtin_amdgcn_mfma_f32_16x16x16bf16_1k(
                        av, bp[qb], o_[db][qb], 0, 0, 0);
            }
            __builtin_amdgcn_s_setprio(0);

            __syncthreads();   // publish stg buffer + fence buffer rotation

            ushort_t* tk = Kcur; Kcur = Knxt; Knxt = Kstg; Kstg = tk;
            ushort_t* tv = Vcur; Vcur = Vnxt; Vnxt = Vstg; Vstg = tv;
            if (t + 1 < nt) {
                #pragma unroll
                for (int qb = 0; qb < 4; ++qb) scA[qb] = scB[qb];
            }
        }

        #pragma unroll
        for (int qb = 0; qb < 4; ++qb) {
            lq[qb] += __shfl_xor(lq[qb], 16);
            lq[qb] += __shfl_xor(lq[qb], 32);
        }
        if (quad == 0) {
            #pragma unroll
            for (int qb = 0; qb < 4; ++qb) Lred[w * 64 + qb * 16 + col] = lq[qb];
        }
        {
            float* myreg = Ored + w * 4096;
            #pragma unroll
            for (int db = 0; db < 4; ++db)
                #pragma unroll
                for (int qb = 0; qb < 4; ++qb) {
                    int q = qb * 16 + col;
                    int swch = (db * 4 + quad) ^ col;
                    *(floatx4*)(myreg + q * 64 + swch * 4) = o_[db][qb];
                }
        }
        __syncthreads();

        {
            const int qloc = w * 16 + (lane >> 2);
            float lsum = Lred[qloc] + Lred[64 + qloc] + Lred[128 + qloc] + Lred[192 + qloc];
            float linv = 1.f / lsum;
            const int dc0 = (lane & 3) * 4;        // 4 d-chunks of 4 floats
            floatx4 acc[4];
            #pragma unroll
            for (int j = 0; j < 4; ++j) {
                int swch = (dc0 + j) ^ (qloc & 15);
                const float* p = Ored + (size_t)qloc * 64 + swch * 4;
                floatx4 a = *(const floatx4*)p;
                a += *(const floatx4*)(p + 4096);
                a += *(const floatx4*)(p + 8192);
                a += *(const floatx4*)(p + 12288);
                acc[j] = a;
            }
            const size_t rowb = ((size_t)(b * SEQ + q0 + qloc)) * D_MODEL + h * HDIM + dc0 * 4;
            uint4 u0, u1;
            u0.x = pkbf(acc[0][0] * linv, acc[0][1] * linv);
            u0.y = pkbf(acc[0][2] * linv, acc[0][3] * linv);
            u0.z = pkbf(acc[1][0] * linv, acc[1][1] * linv);
            u0.w = pkbf(acc[1][2] * linv, acc[1][3] * linv);
            u1.x = pkbf(acc[2][0] * linv, acc[2][1] * linv);
            u1.y = pkbf(acc[2][2] * linv, acc[2][3] * linv);
            u1.z = pkbf(acc[3][0] * linv, acc[3][1] * linv);
            u1.w = pkbf(acc[3][2] * linv, acc[3][3] * linv);
            *(uint4*)(H + rowb) = u0;
            *(uint4*)(H + rowb + 8) = u1;
        }
    }
}

extern "C" void kernel_launch(void* const* d_in, const int* in_sizes, int n_in,
                              void* d_out, int out_size, void* d_ws, size_t ws_size,
                              hipStream_t stream)
{
    (void)in_sizes; (void)n_in; (void)out_size; (void)ws_size;
    const float* x  = (const float*)d_in[0];
    const float* Wq = (const float*)d_in[1];
    const float* bq = (const float*)d_in[2];
    const float* Wk = (const float*)d_in[3];
    const float* bk = (const float*)d_in[4];
    const float* Wv = (const float*)d_in[5];
    const float* bv = (const float*)d_in[6];
    const float* Wo = (const float*)d_in[7];
    const float* bo = (const float*)d_in[8];

    const size_t E = (size_t)MROWS * D_MODEL;
    ushort_t* xb    = (ushort_t*)d_ws;               // [4096][1024] bf16
    ushort_t* WtQKV = xb + E;                        // [3072][1024] bf16
    ushort_t* WtO   = WtQKV + 3 * (size_t)D_MODEL * KDIM;
    ushort_t* Qb    = WtO + (size_t)D_MODEL * KDIM;  // [b,h,s,d] bf16 (pre-scaled)
    ushort_t* Kb    = Qb + E;                        // [b,h,s,d] bf16
    ushort_t* Vb    = Kb + E;                        // [b,h,d,s] bf16 (transposed)
    ushort_t* Hb    = Vb + E;                        // [4096][1024] bf16

    cvt_all<<<dim3(32, 32, 5), 256, 0, stream>>>(x, Wq, Wk, Wv, Wo, xb, WtQKV, WtO);
    gemm_qkv<<<dim3(24, 32), 128, 0, stream>>>(xb, WtQKV, bq, bk, bv, Qb, Kb, Vb);
    attn_mfma<<<dim3(512), 256, 0, stream>>>(Qb, Kb, Vb, Hb);
    gemm_o<<<dim3(16, 32), 128, 0, stream>>>(Hb, WtO, bo, (float*)d_out);
}